// Round 1
// baseline (108.424 us; speedup 1.0000x reference)
//
#include <hip/hip_runtime.h>
#include <hip/hip_fp16.h>

typedef _Float16 f16x8 __attribute__((ext_vector_type(8)));
typedef float f32x4 __attribute__((ext_vector_type(4)));

// Workspace layout (bytes):
//   qv     [0,       65536)   : 32x512 f32   q = query @ Wq^T
//   bfrag  [65536,   589824)  : 512x512 f16  Wk^T in MFMA-fragment-major layout
//   scores [589824,  851968)  : 32x2048 f32  pre-softmax scores
//   vpart  [851968, 2949120)  : 32x32x512 f32 partial attn@values
#define WS_QV 0
#define WS_BF 65536
#define WS_SC 589824
#define WS_VP 851968

// ---------------- P: qv = query@Wq^T (fp32) + prepack Wk -> fp16 fragment layout ----
__global__ __launch_bounds__(256) void prep_kernel(
    const float* __restrict__ query, const float* __restrict__ Wq,
    const float* __restrict__ Wk, float* __restrict__ qv,
    _Float16* __restrict__ bfrag) {
  const int blk = blockIdx.x, tid = threadIdx.x;
  if (blk < 64) {
    // qv[b][h] = sum_d query[b][d] * Wq[h][d]
    const int b = blk >> 1;
    const int h = ((blk & 1) << 8) + tid;
    const float4* qr = (const float4*)(query + (size_t)b * 512);
    const float4* wr = (const float4*)(Wq + (size_t)h * 512);
    float acc = 0.f;
#pragma unroll 8
    for (int i = 0; i < 128; ++i) {
      float4 a = qr[i], w = wr[i];
      acc += a.x * w.x + a.y * w.y + a.z * w.z + a.w * w.w;
    }
    qv[b * 512 + h] = acc;
  } else {
    // B-fragment for mfma_f32_16x16x32_f16:
    // unit u = nt*16 + ks  (nt: 16-col tile of h, ks: 32-wide k step)
    // lane l supplies B[k = 32*ks + 8*(l>>4)+e][col = 16*nt + (l&15)] = Wk[col][k]
    const int u = (blk - 64) * 4 + (tid >> 6);   // 512 units total
    const int l = tid & 63;
    const int col = ((u >> 4) << 4) + (l & 15);
    const int k0 = ((u & 15) << 5) + ((l >> 4) << 3);
    const float4* src = (const float4*)(Wk + (size_t)col * 512 + k0);
    float4 x = src[0], y = src[1];
    f16x8 v;
    v[0] = (_Float16)x.x; v[1] = (_Float16)x.y;
    v[2] = (_Float16)x.z; v[3] = (_Float16)x.w;
    v[4] = (_Float16)y.x; v[5] = (_Float16)y.y;
    v[6] = (_Float16)y.z; v[7] = (_Float16)y.w;
    *(f16x8*)(bfrag + (size_t)u * 512 + l * 8) = v;
  }
}

// ---------------- S: fused keys@Wk^T -> tanh(qv + .) . w_att -> scores -------------
// Grid 1024: wg handles 64 rows of M=B*S. 4 waves, wave w owns h-cols [128w,128w+128).
// keys tile staged as fp16 in XOR-swizzled LDS (64 KiB, 2 wg/CU). B frags in regs.
__global__ __launch_bounds__(256, 2) void scores_kernel(
    const float* __restrict__ keys, const _Float16* __restrict__ bfrag,
    const float* __restrict__ qv, const float* __restrict__ w_att,
    float* __restrict__ scores) {
  __shared__ __align__(128) unsigned char lds[65536];
  const int tid = threadIdx.x, w = tid >> 6, l = tid & 63;
  const int wg = blockIdx.x;
  const int row0 = wg * 64;
  const int b = row0 >> 11;   // 2048 rows per batch, 64 | 2048

  // ---- stage keys[row0..row0+64) x 512 fp32 -> fp16 LDS, swizzled
  {
    const float* kb = keys + (size_t)row0 * 512;
#pragma unroll
    for (int j = 0; j < 16; ++j) {
      int u8 = j * 256 + tid;            // 8-float unit
      int r = u8 >> 6, c8 = u8 & 63;
      const float4* src = (const float4*)(kb + (size_t)r * 512 + c8 * 8);
      float4 x = src[0], y = src[1];
      f16x8 v;
      v[0] = (_Float16)x.x; v[1] = (_Float16)x.y;
      v[2] = (_Float16)x.z; v[3] = (_Float16)x.w;
      v[4] = (_Float16)y.x; v[5] = (_Float16)y.y;
      v[6] = (_Float16)y.z; v[7] = (_Float16)y.w;
      int byte = r * 1024 + c8 * 16;
      byte ^= (r & 7) << 4;              // bank swizzle
      *(f16x8*)(lds + byte) = v;
    }
  }
  __syncthreads();

  f32x4 acc[4][8];
#pragma unroll
  for (int mt = 0; mt < 4; ++mt)
#pragma unroll
    for (int nt = 0; nt < 8; ++nt) {
      acc[mt][nt][0] = 0.f; acc[mt][nt][1] = 0.f;
      acc[mt][nt][2] = 0.f; acc[mt][nt][3] = 0.f;
    }

  const int swz = (l & 7) << 4;              // row&7 == l&7 for all m-tiles
  const int acol = ((l >> 4) << 3) * 2;      // k-slot byte offset within step
  const int arow = (l & 15) * 1024;

  // ---- main loop: K=512 as 8 chunks x (2 k-steps of 32)
#pragma unroll
  for (int kc = 0; kc < 8; ++kc) {
    f16x8 bf[8][2];
#pragma unroll
    for (int nt = 0; nt < 8; ++nt)
#pragma unroll
      for (int k2 = 0; k2 < 2; ++k2) {
        int u = (w * 8 + nt) * 16 + (kc * 2 + k2);
        bf[nt][k2] = *(const f16x8*)(bfrag + (size_t)u * 512 + l * 8);
      }
#pragma unroll
    for (int k2 = 0; k2 < 2; ++k2) {
      const int ks = kc * 2 + k2;
      f16x8 af[4];
#pragma unroll
      for (int mt = 0; mt < 4; ++mt) {
        int byte = (mt * 16384 + arow) + (ks * 64 + acol);
        byte ^= swz;
        af[mt] = *(const f16x8*)(lds + byte);
      }
#pragma unroll
      for (int mt = 0; mt < 4; ++mt)
#pragma unroll
        for (int nt = 0; nt < 8; ++nt)
          acc[mt][nt] = __builtin_amdgcn_mfma_f32_16x16x32_f16(
              af[mt], bf[nt][k2], acc[mt][nt], 0, 0, 0);
    }
  }

  // ---- epilogue: tanh(qv + k) * w_att, reduce over h
  float rs[16];
#pragma unroll
  for (int i = 0; i < 16; ++i) rs[i] = 0.f;
  const int hb = w * 128;
#pragma unroll
  for (int nt = 0; nt < 8; ++nt) {
    const int h = hb + nt * 16 + (l & 15);
    const float q = qv[b * 512 + h];
    const float wa = w_att[h];
#pragma unroll
    for (int mt = 0; mt < 4; ++mt)
#pragma unroll
      for (int r = 0; r < 4; ++r) {
        float x = q + acc[mt][nt][r];
        float e = __expf(x + x);                       // e^{2x}
        float t = 1.f - __fdividef(2.f, e + 1.f);      // tanh(x)
        rs[mt * 4 + r] = __builtin_fmaf(t, wa, rs[mt * 4 + r]);
      }
  }
  // reduce over the 16 col-lanes (l&15)
#pragma unroll
  for (int st = 1; st <= 8; st <<= 1)
#pragma unroll
    for (int i = 0; i < 16; ++i)
      rs[i] += __shfl_xor(rs[i], st, 64);

  __syncthreads();                 // all LDS A-reads done; reuse LDS for partials
  float* spart = (float*)lds;      // [4 waves][64 rows]
  {
    const int idx = l & 15;
    float v = rs[0];
#pragma unroll
    for (int i = 1; i < 16; ++i) v = (idx == i) ? rs[i] : v;   // static-index select
    // row for (mt=idx>>2, r=idx&3): 16*mt + 4*(l>>4) + r
    const int rrow = ((idx >> 2) << 4) + ((l >> 4) << 2) + (idx & 3);
    spart[w * 64 + rrow] = v;
  }
  __syncthreads();
  if (tid < 64) {
    float s = spart[tid] + spart[64 + tid] + spart[128 + tid] + spart[192 + tid];
    scores[row0 + tid] = s;
  }
}

// ---------------- V: softmax (redundant per block) + attn chunk + partial attn@keys
// Grid 32*32: block (b, sc) handles s in [64*sc, 64*sc+64).
__global__ __launch_bounds__(256) void out_kernel(
    const float* __restrict__ keys, const float* __restrict__ scores,
    float* __restrict__ attn_out, float* __restrict__ vpart) {
  __shared__ float red_mx[4], red_se[4];
  const int tid = threadIdx.x;
  const int b = blockIdx.x >> 5;
  const int sc = blockIdx.x & 31;
  const float* srow = scores + (size_t)b * 2048;

  float sv[8];
  float mx = -1e30f;
#pragma unroll
  for (int i = 0; i < 8; ++i) { sv[i] = srow[i * 256 + tid]; mx = fmaxf(mx, sv[i]); }
#pragma unroll
  for (int st = 32; st >= 1; st >>= 1) mx = fmaxf(mx, __shfl_xor(mx, st, 64));
  if ((tid & 63) == 0) red_mx[tid >> 6] = mx;
  __syncthreads();
  mx = fmaxf(fmaxf(red_mx[0], red_mx[1]), fmaxf(red_mx[2], red_mx[3]));

  float se = 0.f;
#pragma unroll
  for (int i = 0; i < 8; ++i) se += __expf(sv[i] - mx);
#pragma unroll
  for (int st = 32; st >= 1; st >>= 1) se += __shfl_xor(se, st, 64);
  if ((tid & 63) == 0) red_se[tid >> 6] = se;
  __syncthreads();
  se = red_se[0] + red_se[1] + red_se[2] + red_se[3];
  const float rinv = 1.f / se;

  if (tid < 64) {
    int s = sc * 64 + tid;
    attn_out[(size_t)b * 2048 + s] = __expf(srow[s] - mx) * rinv;
  }

  float acc0 = 0.f, acc1 = 0.f;
  const float* kb = keys + ((size_t)(b * 2048 + sc * 64)) * 512;
#pragma unroll 4
  for (int i = 0; i < 64; ++i) {
    float at = __expf(srow[sc * 64 + i] - mx) * rinv;
    acc0 = __builtin_fmaf(at, kb[(size_t)i * 512 + tid], acc0);
    acc1 = __builtin_fmaf(at, kb[(size_t)i * 512 + tid + 256], acc1);
  }
  vpart[(size_t)blockIdx.x * 512 + tid] = acc0;
  vpart[(size_t)blockIdx.x * 512 + tid + 256] = acc1;
}

// ---------------- V2: reduce 32 partials -> out ------------------------------------
__global__ __launch_bounds__(256) void reduce_kernel(
    const float* __restrict__ vpart, float* __restrict__ out) {
  const int t = blockIdx.x * 256 + threadIdx.x;   // 16384 outputs
  const int b = t >> 9, d = t & 511;
  float s = 0.f;
#pragma unroll
  for (int sc = 0; sc < 32; ++sc)
    s += vpart[((size_t)(b * 32 + sc)) * 512 + d];
  out[t] = s;
}

extern "C" void kernel_launch(void* const* d_in, const int* in_sizes, int n_in,
                              void* d_out, int out_size, void* d_ws, size_t ws_size,
                              hipStream_t stream) {
  const float* query = (const float*)d_in[0];   // [32,512]
  const float* keys  = (const float*)d_in[1];   // [32,2048,512]
  const float* Wq    = (const float*)d_in[2];   // [512,512]
  const float* Wk    = (const float*)d_in[3];   // [512,512]
  const float* w_att = (const float*)d_in[4];   // [512]
  float* out  = (float*)d_out;                  // [32,512]
  float* attn = out + 16384;                    // [32,2048]
  char* ws = (char*)d_ws;
  float*    qv     = (float*)(ws + WS_QV);
  _Float16* bfrag  = (_Float16*)(ws + WS_BF);
  float*    scores = (float*)(ws + WS_SC);
  float*    vpart  = (float*)(ws + WS_VP);

  prep_kernel<<<192, 256, 0, stream>>>(query, Wq, Wk, qv, bfrag);
  scores_kernel<<<1024, 256, 0, stream>>>(keys, bfrag, qv, w_att, scores);
  out_kernel<<<1024, 256, 0, stream>>>(keys, scores, attn, vpart);
  reduce_kernel<<<64, 256, 0, stream>>>(vpart, out);
}

// Round 2
// 100.459 us; speedup vs baseline: 1.0793x; 1.0793x over previous
//
#include <hip/hip_runtime.h>
#include <hip/hip_fp16.h>

typedef _Float16 f16x8 __attribute__((ext_vector_type(8)));
typedef float f32x4 __attribute__((ext_vector_type(4)));

// Workspace layout (bytes):
//   qv     [0,       65536)   : 32x512 f32   q = query @ Wq^T
//   bfrag  [65536,   589824)  : 512x512 f16  Wk^T in MFMA-fragment-major layout
//   scores [589824,  851968)  : 32x2048 f32  pre-softmax scores
//   vpart  [851968, 2949120)  : 32x32x512 f32 partial attn@values
#define WS_QV 0
#define WS_BF 65536
#define WS_SC 589824
#define WS_VP 851968

// ---------------- P: qv = query@Wq^T (fp32) + prepack Wk -> fp16 fragment layout ----
__global__ __launch_bounds__(256) void prep_kernel(
    const float* __restrict__ query, const float* __restrict__ Wq,
    const float* __restrict__ Wk, float* __restrict__ qv,
    _Float16* __restrict__ bfrag) {
  const int blk = blockIdx.x, tid = threadIdx.x;
  if (blk < 64) {
    const int b = blk >> 1;
    const int h = ((blk & 1) << 8) + tid;
    const float4* qr = (const float4*)(query + (size_t)b * 512);
    const float4* wr = (const float4*)(Wq + (size_t)h * 512);
    float acc = 0.f;
#pragma unroll 8
    for (int i = 0; i < 128; ++i) {
      float4 a = qr[i], w = wr[i];
      acc += a.x * w.x + a.y * w.y + a.z * w.z + a.w * w.w;
    }
    qv[b * 512 + h] = acc;
  } else {
    // B-fragment for mfma_f32_16x16x32_f16: unit u = nt*16 + ks
    // lane l supplies B[k = 32*ks + 8*(l>>4)+e][col = 16*nt + (l&15)] = Wk[col][k]
    const int u = (blk - 64) * 4 + (tid >> 6);
    const int l = tid & 63;
    const int col = ((u >> 4) << 4) + (l & 15);
    const int k0 = ((u & 15) << 5) + ((l >> 4) << 3);
    const float4* src = (const float4*)(Wk + (size_t)col * 512 + k0);
    float4 x = src[0], y = src[1];
    f16x8 v;
    v[0] = (_Float16)x.x; v[1] = (_Float16)x.y;
    v[2] = (_Float16)x.z; v[3] = (_Float16)x.w;
    v[4] = (_Float16)y.x; v[5] = (_Float16)y.y;
    v[6] = (_Float16)y.z; v[7] = (_Float16)y.w;
    *(f16x8*)(bfrag + (size_t)u * 512 + l * 8) = v;
  }
}

// ---------------- S: fused keys@Wk^T -> tanh(qv + .) . w_att -> scores -------------
// Grid 1024 x 256 threads. wg = 64 rows; wave w owns h-cols [128w, 128w+128).
// K split into 4 chunks of 128, double-buffered fp16 LDS (2 x 16 KiB).
// Pipeline per chunk: issue next-chunk global loads -> compute -> cvt+write -> barrier.
__global__ __launch_bounds__(256, 2) void scores_kernel(
    const float* __restrict__ keys, const _Float16* __restrict__ bfrag,
    const float* __restrict__ qv, const float* __restrict__ w_att,
    float* __restrict__ scores) {
  __shared__ __align__(128) unsigned char lds[32768];   // 2 x (64 rows x 128 k fp16)
  const int tid = threadIdx.x, w = tid >> 6, l = tid & 63;
  const int row0 = blockIdx.x * 64;
  const int b = row0 >> 11;

  // staging: thread owns row sr, 32 floats at col scb*32 (per chunk)
  const int sr = tid >> 2, scb = tid & 3;
  const float* gsrc = keys + (size_t)(row0 + sr) * 512 + scb * 32;
  const int wbase = sr * 256 + scb * 64;      // byte offset in chunk buffer
  const int wswz = (sr & 7) << 4;

  float4 stg[8];
#pragma unroll
  for (int j = 0; j < 8; ++j) stg[j] = ((const float4*)gsrc)[j];
  {
    unsigned char* dbuf = lds;
#pragma unroll
    for (int j2 = 0; j2 < 4; ++j2) {
      float4 x = stg[2 * j2], y = stg[2 * j2 + 1];
      f16x8 h;
      h[0] = (_Float16)x.x; h[1] = (_Float16)x.y;
      h[2] = (_Float16)x.z; h[3] = (_Float16)x.w;
      h[4] = (_Float16)y.x; h[5] = (_Float16)y.y;
      h[6] = (_Float16)y.z; h[7] = (_Float16)y.w;
      *(f16x8*)(dbuf + ((wbase + j2 * 16) ^ wswz)) = h;
    }
  }
  __syncthreads();

  f32x4 acc[4][8];
#pragma unroll
  for (int mt = 0; mt < 4; ++mt)
#pragma unroll
    for (int nt = 0; nt < 8; ++nt) {
      acc[mt][nt][0] = 0.f; acc[mt][nt][1] = 0.f;
      acc[mt][nt][2] = 0.f; acc[mt][nt][3] = 0.f;
    }

  const int aswz = (l & 7) << 4;
  const int arow = (l & 15) * 256;
  const int acol = (l >> 4) << 4;

#pragma unroll
  for (int c = 0; c < 4; ++c) {
    // ---- issue global loads for chunk c+1 (in flight during compute)
    if (c < 3) {
      const float4* g = (const float4*)(gsrc + (c + 1) * 128);
#pragma unroll
      for (int j = 0; j < 8; ++j) stg[j] = g[j];
    }
    __builtin_amdgcn_sched_barrier(0);

    // ---- compute chunk c from buf[c&1]
    const unsigned char* buf = lds + (c & 1) * 16384;
#pragma unroll
    for (int kl = 0; kl < 4; ++kl) {
      const int ks = c * 4 + kl;
      f16x8 bf[8];
#pragma unroll
      for (int nt = 0; nt < 8; ++nt) {
        int u = (w * 8 + nt) * 16 + ks;
        bf[nt] = *(const f16x8*)(bfrag + (size_t)u * 512 + l * 8);
      }
      f16x8 af[4];
#pragma unroll
      for (int mt = 0; mt < 4; ++mt) {
        int byte = mt * 4096 + arow + ((kl * 64 + acol) ^ aswz);
        af[mt] = *(const f16x8*)(buf + byte);
      }
#pragma unroll
      for (int mt = 0; mt < 4; ++mt)
#pragma unroll
        for (int nt = 0; nt < 8; ++nt)
          acc[mt][nt] = __builtin_amdgcn_mfma_f32_16x16x32_f16(
              af[mt], bf[nt], acc[mt][nt], 0, 0, 0);
    }
    __builtin_amdgcn_sched_barrier(0);

    // ---- cvt + write chunk c+1
    if (c < 3) {
      unsigned char* dbuf = lds + ((c + 1) & 1) * 16384;
#pragma unroll
      for (int j2 = 0; j2 < 4; ++j2) {
        float4 x = stg[2 * j2], y = stg[2 * j2 + 1];
        f16x8 h;
        h[0] = (_Float16)x.x; h[1] = (_Float16)x.y;
        h[2] = (_Float16)x.z; h[3] = (_Float16)x.w;
        h[4] = (_Float16)y.x; h[5] = (_Float16)y.y;
        h[6] = (_Float16)y.z; h[7] = (_Float16)y.w;
        *(f16x8*)(dbuf + ((wbase + j2 * 16) ^ wswz)) = h;
      }
    }
    __syncthreads();
  }

  // ---- epilogue: tanh(qv + k) * w_att, reduce over h
  float rs[16];
#pragma unroll
  for (int i = 0; i < 16; ++i) rs[i] = 0.f;
  const int hb = w * 128;
#pragma unroll
  for (int nt = 0; nt < 8; ++nt) {
    const int h = hb + nt * 16 + (l & 15);
    const float q = qv[b * 512 + h];
    const float wa = w_att[h];
#pragma unroll
    for (int mt = 0; mt < 4; ++mt)
#pragma unroll
      for (int r = 0; r < 4; ++r) {
        float x = q + acc[mt][nt][r];
        float e = __expf(x + x);
        float t = 1.f - __fdividef(2.f, e + 1.f);
        rs[mt * 4 + r] = __builtin_fmaf(t, wa, rs[mt * 4 + r]);
      }
  }
#pragma unroll
  for (int st = 1; st <= 8; st <<= 1)
#pragma unroll
    for (int i = 0; i < 16; ++i)
      rs[i] += __shfl_xor(rs[i], st, 64);

  __syncthreads();
  float* spart = (float*)lds;      // [4 waves][64 rows]
  {
    const int idx = l & 15;
    float v = rs[0];
#pragma unroll
    for (int i = 1; i < 16; ++i) v = (idx == i) ? rs[i] : v;
    const int rrow = ((idx >> 2) << 4) + ((l >> 4) << 2) + (idx & 3);
    spart[w * 64 + rrow] = v;
  }
  __syncthreads();
  if (tid < 64) {
    float s = spart[tid] + spart[64 + tid] + spart[128 + tid] + spart[192 + tid];
    scores[row0 + tid] = s;
  }
}

// ---------------- V: softmax (redundant per block) + attn chunk + partial attn@keys
__global__ __launch_bounds__(256) void out_kernel(
    const float* __restrict__ keys, const float* __restrict__ scores,
    float* __restrict__ attn_out, float* __restrict__ vpart) {
  __shared__ float red_mx[4], red_se[4];
  __shared__ float4 comb[128];
  const int tid = threadIdx.x;
  const int b = blockIdx.x >> 5;
  const int sc = blockIdx.x & 31;
  const float* srow = scores + (size_t)b * 2048;

  float sv[8];
  float mx = -1e30f;
#pragma unroll
  for (int i = 0; i < 8; ++i) { sv[i] = srow[i * 256 + tid]; mx = fmaxf(mx, sv[i]); }
#pragma unroll
  for (int st = 32; st >= 1; st >>= 1) mx = fmaxf(mx, __shfl_xor(mx, st, 64));
  if ((tid & 63) == 0) red_mx[tid >> 6] = mx;
  __syncthreads();
  mx = fmaxf(fmaxf(red_mx[0], red_mx[1]), fmaxf(red_mx[2], red_mx[3]));

  float se = 0.f;
#pragma unroll
  for (int i = 0; i < 8; ++i) se += __expf(sv[i] - mx);
#pragma unroll
  for (int st = 32; st >= 1; st >>= 1) se += __shfl_xor(se, st, 64);
  if ((tid & 63) == 0) red_se[tid >> 6] = se;
  __syncthreads();
  se = red_se[0] + red_se[1] + red_se[2] + red_se[3];
  const float rinv = 1.f / se;

  if (tid < 64) {
    int s = sc * 64 + tid;
    attn_out[(size_t)b * 2048 + s] = __expf(srow[s] - mx) * rinv;
  }

  // acc: thread -> col4 (c4), row-group rg of 32 rows; float4 loads
  const int c4 = tid & 127, rg = tid >> 7;
  const float4* kb4 = (const float4*)(keys + ((size_t)(b * 2048 + sc * 64 + rg * 32)) * 512);
  float4 a; a.x = 0.f; a.y = 0.f; a.z = 0.f; a.w = 0.f;
#pragma unroll 4
  for (int i = 0; i < 32; ++i) {
    float at = __expf(srow[sc * 64 + rg * 32 + i] - mx) * rinv;
    float4 kv = kb4[(size_t)i * 128 + c4];
    a.x = __builtin_fmaf(at, kv.x, a.x);
    a.y = __builtin_fmaf(at, kv.y, a.y);
    a.z = __builtin_fmaf(at, kv.z, a.z);
    a.w = __builtin_fmaf(at, kv.w, a.w);
  }
  if (rg) comb[c4] = a;
  __syncthreads();
  if (!rg) {
    float4 o = comb[c4];
    a.x += o.x; a.y += o.y; a.z += o.z; a.w += o.w;
    ((float4*)vpart)[(size_t)blockIdx.x * 128 + c4] = a;
  }
}

// ---------------- V2: reduce 32 partials -> out ------------------------------------
__global__ __launch_bounds__(256) void reduce_kernel(
    const float* __restrict__ vpart, float* __restrict__ out) {
  const int t = blockIdx.x * 256 + threadIdx.x;
  const int b = t >> 9, d = t & 511;
  float s = 0.f;
#pragma unroll
  for (int sc = 0; sc < 32; ++sc)
    s += vpart[((size_t)(b * 32 + sc)) * 512 + d];
  out[t] = s;
}

extern "C" void kernel_launch(void* const* d_in, const int* in_sizes, int n_in,
                              void* d_out, int out_size, void* d_ws, size_t ws_size,
                              hipStream_t stream) {
  const float* query = (const float*)d_in[0];
  const float* keys  = (const float*)d_in[1];
  const float* Wq    = (const float*)d_in[2];
  const float* Wk    = (const float*)d_in[3];
  const float* w_att = (const float*)d_in[4];
  float* out  = (float*)d_out;                  // [32,512]
  float* attn = out + 16384;                    // [32,2048]
  char* ws = (char*)d_ws;
  float*    qv     = (float*)(ws + WS_QV);
  _Float16* bfrag  = (_Float16*)(ws + WS_BF);
  float*    scores = (float*)(ws + WS_SC);
  float*    vpart  = (float*)(ws + WS_VP);

  prep_kernel<<<192, 256, 0, stream>>>(query, Wq, Wk, qv, bfrag);
  scores_kernel<<<1024, 256, 0, stream>>>(keys, bfrag, qv, w_att, scores);
  out_kernel<<<1024, 256, 0, stream>>>(keys, scores, attn, vpart);
  reduce_kernel<<<64, 256, 0, stream>>>(vpart, out);
}

// Round 3
// 91.042 us; speedup vs baseline: 1.1909x; 1.1034x over previous
//
#include <hip/hip_runtime.h>
#include <hip/hip_fp16.h>

typedef _Float16 f16x8 __attribute__((ext_vector_type(8)));
typedef _Float16 f16x2 __attribute__((ext_vector_type(2)));
typedef float f32x4 __attribute__((ext_vector_type(4)));

// Workspace layout (bytes):
//   qv     [0,       65536)   : 32x512 f32   q = query @ Wq^T
//   bfrag  [65536,   589824)  : 512x512 f16  Wk^T in MFMA-fragment-major layout
//   scores [589824,  851968)  : 32x2048 f32  pre-softmax scores
//   vpart  [851968, 2949120)  : 1024x512 f32 per-tile unnormalized attn@keys
//   stats  [2949120, 2957312) : 1024x2 f32   per-tile (m, l)
#define WS_QV 0
#define WS_BF 65536
#define WS_SC 589824
#define WS_VP 851968
#define WS_ST 2949120

// ---------------- P: qv = query@Wq^T (fp32) + prepack Wk -> fp16 fragment layout ----
__global__ __launch_bounds__(256) void prep_kernel(
    const float* __restrict__ query, const float* __restrict__ Wq,
    const float* __restrict__ Wk, float* __restrict__ qv,
    _Float16* __restrict__ bfrag) {
  const int blk = blockIdx.x, tid = threadIdx.x;
  if (blk < 64) {
    const int b = blk >> 1;
    const int h = ((blk & 1) << 8) + tid;
    const float4* qr = (const float4*)(query + (size_t)b * 512);
    const float4* wr = (const float4*)(Wq + (size_t)h * 512);
    float acc = 0.f;
#pragma unroll 8
    for (int i = 0; i < 128; ++i) {
      float4 a = qr[i], w = wr[i];
      acc += a.x * w.x + a.y * w.y + a.z * w.z + a.w * w.w;
    }
    qv[b * 512 + h] = acc;
  } else {
    // B-fragment for mfma_f32_16x16x32_f16: unit u = nt*16 + ks
    // lane l supplies B[k = 32*ks + 8*(l>>4)+e][col = 16*nt + (l&15)] = Wk[col][k]
    const int u = (blk - 64) * 4 + (tid >> 6);
    const int l = tid & 63;
    const int col = ((u >> 4) << 4) + (l & 15);
    const int k0 = ((u & 15) << 5) + ((l >> 4) << 3);
    const float4* src = (const float4*)(Wk + (size_t)col * 512 + k0);
    float4 x = src[0], y = src[1];
    f16x8 v;
    v[0] = (_Float16)x.x; v[1] = (_Float16)x.y;
    v[2] = (_Float16)x.z; v[3] = (_Float16)x.w;
    v[4] = (_Float16)y.x; v[5] = (_Float16)y.y;
    v[6] = (_Float16)y.z; v[7] = (_Float16)y.w;
    *(f16x8*)(bfrag + (size_t)u * 512 + l * 8) = v;
  }
}

// ---------------- F: fused keys@Wk^T -> tanh -> scores -> tile softmax -> attn@keys
// Grid 1024: wg = 64 rows of one batch. 4 waves; wave w owns h-cols [128w, 128w+128).
// Keys tile 64x512 fp16 lives in LDS (4 quarters of 128 k-cols, XOR-swizzled rows);
// quarter c+1 is reg-staged from HBM while quarter c feeds the MFMAs.
__global__ __launch_bounds__(256, 2) void fused_kernel(
    const float* __restrict__ keys, const _Float16* __restrict__ bfrag,
    const float* __restrict__ qv, const float* __restrict__ w_att,
    float* __restrict__ scores, float* __restrict__ vpart,
    float* __restrict__ stats) {
  __shared__ __align__(128) unsigned char lds[65536];   // 64 rows x 512 cols fp16
  __shared__ float spart[256];
  __shared__ float pb[64];
  __shared__ float pb2[64];
  const int tid = threadIdx.x, w = tid >> 6, l = tid & 63;
  const int wg = blockIdx.x;
  const int row0 = wg * 64;
  const int b = row0 >> 11;

  // staging: thread owns row sr, 32 floats at chunk-local col scb*32
  const int sr = tid >> 2, scb = tid & 3;
  const float* gsrc = keys + (size_t)(row0 + sr) * 512 + scb * 32;
  const int wbase = sr * 256 + scb * 64;      // byte offset within quarter
  const int wswz = (sr & 7) << 4;

  float4 stg[8];
#pragma unroll
  for (int j = 0; j < 8; ++j) stg[j] = ((const float4*)gsrc)[j];
  {
    unsigned char* dbuf = lds;                // quarter 0
#pragma unroll
    for (int j2 = 0; j2 < 4; ++j2) {
      float4 x = stg[2 * j2], y = stg[2 * j2 + 1];
      f16x8 h;
      h[0] = (_Float16)x.x; h[1] = (_Float16)x.y;
      h[2] = (_Float16)x.z; h[3] = (_Float16)x.w;
      h[4] = (_Float16)y.x; h[5] = (_Float16)y.y;
      h[6] = (_Float16)y.z; h[7] = (_Float16)y.w;
      *(f16x8*)(dbuf + ((wbase + j2 * 16) ^ wswz)) = h;
    }
  }
  __syncthreads();

  f32x4 acc[4][8];
#pragma unroll
  for (int mt = 0; mt < 4; ++mt)
#pragma unroll
    for (int nt = 0; nt < 8; ++nt) {
      acc[mt][nt][0] = 0.f; acc[mt][nt][1] = 0.f;
      acc[mt][nt][2] = 0.f; acc[mt][nt][3] = 0.f;
    }

  const int aswz = (l & 7) << 4;
  const int arow = (l & 15) * 256;
  const int acol = (l >> 4) << 4;

#pragma unroll
  for (int c = 0; c < 4; ++c) {
    // ---- issue global loads for chunk c+1 (in flight during compute)
    if (c < 3) {
      const float4* g = (const float4*)(gsrc + (c + 1) * 128);
#pragma unroll
      for (int j = 0; j < 8; ++j) stg[j] = g[j];
    }
    __builtin_amdgcn_sched_barrier(0);

    // ---- compute chunk c from quarter c
    const unsigned char* buf = lds + c * 16384;
#pragma unroll
    for (int kl = 0; kl < 4; ++kl) {
      const int ks = c * 4 + kl;
      f16x8 bf[8];
#pragma unroll
      for (int nt = 0; nt < 8; ++nt) {
        int u = (w * 8 + nt) * 16 + ks;
        bf[nt] = *(const f16x8*)(bfrag + (size_t)u * 512 + l * 8);
      }
      f16x8 af[4];
#pragma unroll
      for (int mt = 0; mt < 4; ++mt) {
        int byte = mt * 4096 + arow + ((kl * 64 + acol) ^ aswz);
        af[mt] = *(const f16x8*)(buf + byte);
      }
#pragma unroll
      for (int mt = 0; mt < 4; ++mt)
#pragma unroll
        for (int nt = 0; nt < 8; ++nt)
          acc[mt][nt] = __builtin_amdgcn_mfma_f32_16x16x32_f16(
              af[mt], bf[nt], acc[mt][nt], 0, 0, 0);
    }
    __builtin_amdgcn_sched_barrier(0);

    // ---- cvt + write chunk c+1 into quarter c+1
    if (c < 3) {
      unsigned char* dbuf = lds + (c + 1) * 16384;
#pragma unroll
      for (int j2 = 0; j2 < 4; ++j2) {
        float4 x = stg[2 * j2], y = stg[2 * j2 + 1];
        f16x8 h;
        h[0] = (_Float16)x.x; h[1] = (_Float16)x.y;
        h[2] = (_Float16)x.z; h[3] = (_Float16)x.w;
        h[4] = (_Float16)y.x; h[5] = (_Float16)y.y;
        h[6] = (_Float16)y.z; h[7] = (_Float16)y.w;
        *(f16x8*)(dbuf + ((wbase + j2 * 16) ^ wswz)) = h;
      }
      __syncthreads();
    }
  }

  // ---- epilogue: tanh(qv + k) * w_att, reduce over h -> per-row scores
  float rs[16];
#pragma unroll
  for (int i = 0; i < 16; ++i) rs[i] = 0.f;
  const int hb = w * 128;
#pragma unroll
  for (int nt = 0; nt < 8; ++nt) {
    const int h = hb + nt * 16 + (l & 15);
    const float q = qv[b * 512 + h];
    const float wa = w_att[h];
#pragma unroll
    for (int mt = 0; mt < 4; ++mt)
#pragma unroll
      for (int r = 0; r < 4; ++r) {
        float x = q + acc[mt][nt][r];
        float e = __expf(x + x);
        float t = 1.f - __fdividef(2.f, e + 1.f);
        rs[mt * 4 + r] = __builtin_fmaf(t, wa, rs[mt * 4 + r]);
      }
  }
#pragma unroll
  for (int st = 1; st <= 8; st <<= 1)
#pragma unroll
    for (int i = 0; i < 16; ++i)
      rs[i] += __shfl_xor(rs[i], st, 64);

  {
    const int idx = l & 15;
    float v = rs[0];
#pragma unroll
    for (int i = 1; i < 16; ++i) v = (idx == i) ? rs[i] : v;
    const int rrow = ((idx >> 2) << 4) + ((l >> 4) << 2) + (idx & 3);
    spart[w * 64 + rrow] = v;
  }
  __syncthreads();
  if (tid < 64) {
    float s = spart[tid] + spart[64 + tid] + spart[128 + tid] + spart[192 + tid];
    scores[row0 + tid] = s;
    pb[tid] = s;
  }
  __syncthreads();

  // ---- tile softmax stats
  float m = -1e30f;
#pragma unroll 16
  for (int r = 0; r < 64; ++r) m = fmaxf(m, pb[r]);      // broadcast reads
  if (tid < 64) pb2[tid] = __expf(pb[tid] - m);
  __syncthreads();

  // ---- V-partial: vpart[wg][d] = sum_r pb2[r] * K[r][d], keys from LDS fp16
  // thread t handles cols d0 = 2t, 2t+1; quarter = w, chunk-local col byte = 4l.
  {
    float a0 = 0.f, a1 = 0.f;
    const unsigned char* q = lds + w * 16384;
#pragma unroll 8
    for (int r = 0; r < 64; ++r) {
      f16x2 kv = *(const f16x2*)(q + r * 256 + ((4 * l) ^ ((r & 7) << 4)));
      float p = pb2[r];
      a0 = __builtin_fmaf(p, (float)kv[0], a0);
      a1 = __builtin_fmaf(p, (float)kv[1], a1);
    }
    float2 o; o.x = a0; o.y = a1;
    *(float2*)(vpart + (size_t)wg * 512 + 2 * tid) = o;
  }
  if (tid == 0) {
    float lsum = 0.f;
#pragma unroll 16
    for (int r = 0; r < 64; ++r) lsum += pb2[r];
    stats[wg * 2] = m;
    stats[wg * 2 + 1] = lsum;
  }
}

// ---------------- C: combine 32 tiles per batch -> out, attn ----------------------
__global__ __launch_bounds__(256) void combine_kernel(
    const float* __restrict__ vpart, const float* __restrict__ stats,
    const float* __restrict__ scores, float* __restrict__ out,
    float* __restrict__ attn) {
  const int blk = blockIdx.x, tid = threadIdx.x;
  const int b = blk & 31;
  float mt[32], lt[32];
  float M = -1e30f;
#pragma unroll
  for (int t = 0; t < 32; ++t) {
    mt[t] = stats[(b * 32 + t) * 2];
    lt[t] = stats[(b * 32 + t) * 2 + 1];
    M = fmaxf(M, mt[t]);
  }
  float L = 0.f;
#pragma unroll
  for (int t = 0; t < 32; ++t) L += __expf(mt[t] - M) * lt[t];
  const float rinv = 1.f / L;

  if (blk < 32) {
    const int d0 = 2 * tid;
    float a0 = 0.f, a1 = 0.f;
#pragma unroll
    for (int t = 0; t < 32; ++t) {
      float wgt = __expf(mt[t] - M);
      float2 vp = *(const float2*)(vpart + ((size_t)(b * 32 + t)) * 512 + d0);
      a0 = __builtin_fmaf(wgt, vp.x, a0);
      a1 = __builtin_fmaf(wgt, vp.y, a1);
    }
    out[b * 512 + d0] = a0 * rinv;
    out[b * 512 + d0 + 1] = a1 * rinv;
  } else {
#pragma unroll
    for (int j = 0; j < 8; ++j) {
      int s = j * 256 + tid;
      attn[(size_t)b * 2048 + s] = __expf(scores[(size_t)b * 2048 + s] - M) * rinv;
    }
  }
}

extern "C" void kernel_launch(void* const* d_in, const int* in_sizes, int n_in,
                              void* d_out, int out_size, void* d_ws, size_t ws_size,
                              hipStream_t stream) {
  const float* query = (const float*)d_in[0];
  const float* keys  = (const float*)d_in[1];
  const float* Wq    = (const float*)d_in[2];
  const float* Wk    = (const float*)d_in[3];
  const float* w_att = (const float*)d_in[4];
  float* out  = (float*)d_out;                  // [32,512]
  float* attn = out + 16384;                    // [32,2048]
  char* ws = (char*)d_ws;
  float*    qv     = (float*)(ws + WS_QV);
  _Float16* bfrag  = (_Float16*)(ws + WS_BF);
  float*    scores = (float*)(ws + WS_SC);
  float*    vpart  = (float*)(ws + WS_VP);
  float*    stats  = (float*)(ws + WS_ST);

  prep_kernel<<<192, 256, 0, stream>>>(query, Wq, Wk, qv, bfrag);
  fused_kernel<<<1024, 256, 0, stream>>>(keys, bfrag, qv, w_att, scores, vpart, stats);
  combine_kernel<<<64, 256, 0, stream>>>(vpart, stats, scores, out, attn);
}